// Round 1
// baseline (255.422 us; speedup 1.0000x reference)
//
#include <hip/hip_runtime.h>

typedef unsigned short u16;
typedef __bf16 bf16x8 __attribute__((ext_vector_type(8)));
typedef float f32x4 __attribute__((ext_vector_type(4)));

// ---------- bf16 <-> f32 helpers (RNE) ----------
__device__ __forceinline__ u16 f2bf(float f) {
    union { float f; unsigned int u; } v; v.f = f;
    unsigned int u = v.u;
    return (u16)((u + 0x7FFFu + ((u >> 16) & 1u)) >> 16);
}

// ---------- async global->LDS, 16B per lane ----------
__device__ __forceinline__ void load_lds16(const void* g, void* l) {
    __builtin_amdgcn_global_load_lds(
        (const __attribute__((address_space(1))) unsigned int*)g,
        (__attribute__((address_space(3))) unsigned int*)l,
        16, 0, 0);
}

// MODE2 block classes in LPT (longest-first) dispatch order.
// 16 split k-halves (mtiles 15..8, kh 0/1, work = m+1 BK64-iters) interleaved
// with 8 full tiles (mtiles 7..0, work = 2(m+1)) by descending work, so no CU
// gets a late-starting heavy block. h==2 means "full tile".
__constant__ unsigned char cls_m[24] = {15,15,7,14,14,13,13,6,12,12,11,11,5,10,10,9,9,4,8,8,3,2,1,0};
__constant__ unsigned char cls_h[24] = { 0, 1,2, 0, 1, 0, 1,2, 0, 1, 0, 1,2, 0, 1,0,1,2,0,1,2,2,2,2};

// ---------------------------------------------------------------
// fused prep: 0..8191 cast x fp32->bf16; 8192..11263 transpose W;
// 11264..11295 zero rowsum (8192 floats); 11296..15391 zero out rows
// [1024,2048) per batch (the split-K atomicAdd targets in MODE 2).
// ---------------------------------------------------------------
__global__ void __launch_bounds__(256) prep_kernel(
    const float4* __restrict__ X, u16* __restrict__ xb,
    const float* __restrict__ Wq, const float* __restrict__ Wk,
    const float* __restrict__ Wv,
    u16* __restrict__ Oq, u16* __restrict__ Ok, u16* __restrict__ Ov,
    float* __restrict__ rowsum, float4* __restrict__ outz) {
    __shared__ float tile[32][33];
    const int bid = blockIdx.x, tid = threadIdx.x;
    if (bid < 8192) {
        int idx = bid * 256 + tid;
        float4 v = X[idx];
        ushort4 o;
        o.x = f2bf(v.x); o.y = f2bf(v.y); o.z = f2bf(v.z); o.w = f2bf(v.w);
        *(ushort4*)(xb + (size_t)idx * 4) = o;
    } else if (bid < 11264) {
        int id = bid - 8192;
        int zz = id >> 10;
        const float* W = (zz == 0) ? Wq : (zz == 1) ? Wk : Wv;
        u16* O = (zz == 0) ? Oq : (zz == 1) ? Ok : Ov;
        int n0 = (id & 31) * 32, k0 = ((id >> 5) & 31) * 32;
        int tx = tid & 31, ty = tid >> 5;
        #pragma unroll
        for (int j = 0; j < 32; j += 8)
            tile[ty + j][tx] = W[(size_t)(k0 + ty + j) * 1024 + n0 + tx];
        __syncthreads();
        #pragma unroll
        for (int j = 0; j < 32; j += 8)
            O[(size_t)(n0 + ty + j) * 1024 + k0 + tx] = f2bf(tile[tx][ty + j]);
    } else if (bid < 11296) {
        rowsum[(bid - 11264) * 256 + tid] = 0.f;
    } else {
        int i = bid - 11296;                  // 0..4095
        int z = i >> 10;                      // batch
        // zero out[z][rows 1024..2047][:] (fp32): 262144 float4 per batch
        outz[(size_t)z * (2048 * 1024 / 4) + (1024 * 1024 / 4)
             + (size_t)(i & 1023) * 256 + tid] = make_float4(0.f, 0.f, 0.f, 0.f);
    }
}

// ---------------------------------------------------------------
// NT bf16 GEMM, 512 threads = 8 waves (2x4 grid), BK=64 single-buffer
// LDS, stage-all -> barrier -> MFMAs -> barrier. XOR-swizzled chunks:
// conflict-free. XCD-clustered decodes.
//
// MODE 0: QKV projections, 128x128 tiles (1536 blocks = exactly 3 waves
//         of 512 concurrent -> perfect packing; unchanged).
// MODE 1: P~ = exp(QK^T/32 - 12), 128x64 COLUMN-HALF tiles (1536 blocks,
//         1088 live): halves the scheduling quantum so the 544-tile causal
//         set packs into ~1.2 rounds instead of 2. rowsum via shfl+atomic.
// MODE 2: O = (P~ V)/rowsum, 128x128 tiles with SPLIT-K for mtile>=8
//         (two k-halves, fp32 unsafeAtomicAdd into pre-zeroed rows);
//         LPT dispatch via cls_m/cls_h; Vt XCD-local (768 blocks).
// ---------------------------------------------------------------
template <int MODE>
__global__ void __launch_bounds__(512) gemm_nt(
    const u16* __restrict__ xb, const u16* __restrict__ WqT,
    const u16* __restrict__ WkT, const u16* __restrict__ WvT,
    u16* __restrict__ Q, u16* __restrict__ Kb,
    u16* __restrict__ Vt, u16* __restrict__ S,
    float* __restrict__ rowsum, float* __restrict__ out) {

    int mtile, ntile, z, nh = 0, kbeg = 0, kcnt;
    bool split = false;
    const u16 *A, *B;

    if (MODE == 0) {
        int L = blockIdx.x;                       // 1536 blocks
        int c = L & 7, t = (L >> 3) & 7, hi = L >> 6;
        int p = hi * 8 + c;                       // 0..191; mtile&7 == c
        z = p >> 6; mtile = p & 63; ntile = t;
        A = xb;
        B = (z == 0) ? WqT : (z == 1) ? WkT : WvT;
        kcnt = 16;
    } else if (MODE == 1) {
        int id2 = blockIdx.x;                     // 1536 blocks (2 col-halves)
        nh = (id2 >= 768) ? 1 : 0;
        int rr = id2 - nh * 768;
        z = rr / 192;
        int r = rr - z * 192;
        int c = r & 7, g = r >> 3;
        if (g <= c)            { mtile = c;     ntile = g; }
        else if (g < 2*c + 10) { mtile = c + 8; ntile = g - (c + 1); }
        else return;
        A = Q  + (size_t)z * (2048 * 1024);
        B = Kb + (size_t)z * (2048 * 1024);
        kcnt = 16;
    } else {
        int L = blockIdx.x;                       // 768 blocks
        ntile = L & 7;                            // Vt XCD-local
        int j = L >> 3;
        z = j & 3;
        int ci = j >> 2;                          // 0..23, LPT class order
        mtile = cls_m[ci];
        int h = cls_h[ci];
        split = (h != 2);
        kbeg = split ? h * (mtile + 1) : 0;       // BK64 units
        kcnt = split ? (mtile + 1) : (mtile + 1) * 2;
        A = S  + (size_t)z * (2048 * 2048);
        B = Vt + (size_t)z * (1024 * 2048);
    }

    const int LDA = (MODE == 2) ? 2048 : 1024;
    constexpr int NC    = (MODE == 1) ? 1 : 2;    // per-wave B col-frags
    constexpr int BROWS = (MODE == 1) ? 64 : 128; // B-tile rows
    constexpr int BHALF = BROWS * 32;             // u16 per K32-half of Bs

    __shared__ __align__(16) u16 As[128 * 64];
    __shared__ __align__(16) u16 Bs[BROWS * 64];

    const int tid = threadIdx.x;
    const int lane = tid & 63;
    const int wave = tid >> 6;                   // 0..7
    const int wr = wave >> 2, wc = wave & 3;     // 2 x 4 wave grid

    const int r0 = tid >> 2;
    const int kb = (((tid & 3) ^ ((r0 >> 1) & 3))) * 16;   // swizzled chunk

    const char* gA = (const char*)(A + (size_t)(mtile * 128 + r0) * LDA) + kb + kbeg * 128;
    const char* gB = (const char*)(B + (size_t)(ntile * 128 + nh * 64 + r0) * LDA) + kb + kbeg * 128;

    char* lA = (char*)As + tid * 16;
    char* lB = (char*)Bs + tid * 16;

    f32x4 acc[4][NC] = {};

    const int quad = lane >> 4;
    const int l16 = lane & 15;
    const int ch = quad ^ ((l16 >> 1) & 3);      // de-swizzle on read
    const int aoff = (wr * 64 + l16) * 32 + ch * 8;
    const int boff = (wc * 16 * NC + l16) * 32 + ch * 8;

    for (int kt = 0; kt < kcnt; ++kt) {
        load_lds16(gA,      lA);
        load_lds16(gA + 64, lA + 8192);
        if (MODE != 1 || tid < 256) {            // MODE1: 64-row B, waves 0-3
            load_lds16(gB,      lB);
            load_lds16(gB + 64, lB + BHALF * 2);
        }
        gA += 128; gB += 128;
        __syncthreads();

        #pragma unroll
        for (int h2 = 0; h2 < 2; ++h2) {
            const u16* ap = As + h2 * 4096 + aoff;
            const u16* bp = Bs + h2 * BHALF + boff;
            bf16x8 af[4], bfv[NC];
            #pragma unroll
            for (int r = 0; r < 4; ++r) af[r] = *(const bf16x8*)(ap + r * 512);
            #pragma unroll
            for (int c = 0; c < NC; ++c) bfv[c] = *(const bf16x8*)(bp + c * 512);
            #pragma unroll
            for (int r = 0; r < 4; ++r)
                #pragma unroll
                for (int c = 0; c < NC; ++c)
                    acc[r][c] = __builtin_amdgcn_mfma_f32_16x16x32_bf16(
                        af[r], bfv[c], acc[r][c], 0, 0, 0);
        }
        __syncthreads();
    }

    // epilogue — C/D layout: col = lane&15, row = (lane>>4)*4 + reg
    const int grow0 = mtile * 128 + wr * 64 + quad * 4;
    const int gcol0 = ntile * 128 + nh * 64 + wc * 16 * NC + l16;

    if (MODE == 0) {
        if (z < 2) {
            u16* C = z ? Kb : Q;
            #pragma unroll
            for (int r = 0; r < 4; ++r)
                #pragma unroll
                for (int c = 0; c < 2; ++c)
                    #pragma unroll
                    for (int i = 0; i < 4; ++i)
                        C[(size_t)(grow0 + r * 16 + i) * 1024 + gcol0 + c * 16] =
                            f2bf(acc[r][c][i]);
        } else {
            // Vt[b][d][s]: m -> (b,s), n -> d; 4 consecutive i -> consecutive s
            #pragma unroll
            for (int r = 0; r < 4; ++r) {
                int m0 = grow0 + r * 16;
                int b = m0 >> 11, s0 = m0 & 2047;
                #pragma unroll
                for (int c = 0; c < 2; ++c) {
                    int d = gcol0 + c * 16;
                    ushort4 o;
                    o.x = f2bf(acc[r][c][0]); o.y = f2bf(acc[r][c][1]);
                    o.z = f2bf(acc[r][c][2]); o.w = f2bf(acc[r][c][3]);
                    *(ushort4*)(Vt + (size_t)b * (1024 * 2048) + (size_t)d * 2048 + s0) = o;
                }
            }
        }
    } else if (MODE == 1) {
        u16* C = S + (size_t)z * (2048 * 2048);
        float* rs = rowsum + z * 2048;
        const bool diag = (ntile == mtile);
        float rsum[4][4];
        #pragma unroll
        for (int r = 0; r < 4; ++r)
            #pragma unroll
            for (int i = 0; i < 4; ++i) rsum[r][i] = 0.f;
        #pragma unroll
        for (int r = 0; r < 4; ++r)
            #pragma unroll
            for (int i = 0; i < 4; ++i) {
                int grow = grow0 + r * 16 + i;
                int gcol = gcol0;
                float e = 0.f;
                if (!diag || gcol <= grow)
                    e = __expf(acc[r][0][i] * 0.03125f - 12.0f);
                C[(size_t)grow * 2048 + gcol] = f2bf(e);
                rsum[r][i] += e;
            }
        #pragma unroll
        for (int r = 0; r < 4; ++r)
            #pragma unroll
            for (int i = 0; i < 4; ++i) {
                float s = rsum[r][i];
                s += __shfl_xor(s, 1, 64);
                s += __shfl_xor(s, 2, 64);
                s += __shfl_xor(s, 4, 64);
                s += __shfl_xor(s, 8, 64);
                if (l16 == 0)
                    unsafeAtomicAdd(&rs[grow0 + r * 16 + i], s);
            }
    } else {  // MODE 2: normalize by row sums; split tiles accumulate
        const float* rs = rowsum + z * 2048;
        float* C = out + (size_t)z * (2048 * 1024);
        #pragma unroll
        for (int r = 0; r < 4; ++r)
            #pragma unroll
            for (int i = 0; i < 4; ++i) {
                int grow = grow0 + r * 16 + i;
                float inv = 1.0f / rs[grow];
                #pragma unroll
                for (int c = 0; c < 2; ++c) {
                    float vv = acc[r][c][i] * inv;
                    float* p = &C[(size_t)grow * 1024 + gcol0 + c * 16];
                    if (split) unsafeAtomicAdd(p, vv);
                    else       *p = vv;
                }
            }
    }
}

// ---------------------------------------------------------------
// launch
// ---------------------------------------------------------------
extern "C" void kernel_launch(void* const* d_in, const int* in_sizes, int n_in,
                              void* d_out, int out_size, void* d_ws, size_t ws_size,
                              hipStream_t stream) {
    const float* x  = (const float*)d_in[0];
    const float* Wq = (const float*)d_in[1];
    const float* Wk = (const float*)d_in[2];
    const float* Wv = (const float*)d_in[3];
    float* out = (float*)d_out;
    char* ws = (char*)d_ws;
    const size_t Mi = 1u << 20;

    u16* xb  = (u16*)(ws);               // [8192][1024] bf16  16 MiB
    u16* WqT = (u16*)(ws + 16 * Mi);     // [1024][1024] bf16   2 MiB
    u16* WkT = (u16*)(ws + 18 * Mi);
    u16* WvT = (u16*)(ws + 20 * Mi);
    u16* Q   = (u16*)(ws + 22 * Mi);     // [8192][1024] bf16  16 MiB
    u16* Kb  = (u16*)(ws + 38 * Mi);
    u16* Vt  = (u16*)(ws + 54 * Mi);     // [4][1024][2048] bf16 16 MiB
    u16* S   = (u16*)(ws + 70 * Mi);     // [4][2048][2048] bf16 32 MiB (P~)
    float* rowsum = (float*)(ws + 102 * Mi);  // [4][2048] fp32

    // prep: cast x + transpose W + zero rowsum + zero split-K out rows
    prep_kernel<<<15392, 256, 0, stream>>>(
        (const float4*)x, xb, Wq, Wk, Wv, WqT, WkT, WvT, rowsum, (float4*)out);

    // QKV projections (z: 0=Q, 1=K, 2=Vt) — unchanged, perfectly packed
    gemm_nt<0><<<1536, 512, 0, stream>>>(xb, WqT, WkT, WvT, Q, Kb, Vt, S, rowsum, out);

    // P~ = exp(QK^T/32 - 12) + rowsum, causal tiles as 128x64 col-halves
    gemm_nt<1><<<1536, 512, 0, stream>>>(xb, WqT, WkT, WvT, Q, Kb, Vt, S, rowsum, out);

    // O = (P~ V)/rowsum, split-K heavy tiles, LPT order, Vt XCD-local
    gemm_nt<2><<<768, 512, 0, stream>>>(xb, WqT, WkT, WvT, Q, Kb, Vt, S, rowsum, out);
}

// Round 2
// 227.728 us; speedup vs baseline: 1.1216x; 1.1216x over previous
//
#include <hip/hip_runtime.h>

typedef unsigned short u16;
typedef __bf16 bf16x8 __attribute__((ext_vector_type(8)));
typedef float f32x4 __attribute__((ext_vector_type(4)));

// ---------- bf16 <-> f32 helpers (RNE) ----------
__device__ __forceinline__ u16 f2bf(float f) {
    union { float f; unsigned int u; } v; v.f = f;
    unsigned int u = v.u;
    return (u16)((u + 0x7FFFu + ((u >> 16) & 1u)) >> 16);
}

// ---------- async global->LDS, 16B per lane ----------
__device__ __forceinline__ void load_lds16(const void* g, void* l) {
    __builtin_amdgcn_global_load_lds(
        (const __attribute__((address_space(1))) unsigned int*)g,
        (__attribute__((address_space(3))) unsigned int*)l,
        16, 0, 0);
}

// MODE2 block classes in LPT (longest-first) dispatch order.
// 16 split k-halves (mtiles 15..8, kh 0/1, work = m+1 BK64-iters) interleaved
// with 8 full tiles (mtiles 7..0, work = 2(m+1)) by descending work, so no CU
// gets a late-starting heavy block. kh==2 means "full tile".
__constant__ unsigned char cls_m[24] = {15,15,7,14,14,13,13,6,12,12,11,11,5,10,10,9,9,4,8,8,3,2,1,0};
__constant__ unsigned char cls_h[24] = { 0, 1,2, 0, 1, 0, 1,2, 0, 1, 0, 1,2, 0, 1,0,1,2,0,1,2,2,2,2};

// ---------------------------------------------------------------
// fused prep: 0..8191 cast x fp32->bf16; 8192..11263 transpose W;
// 11264..11295 zero rowsum (8192 floats).
// ---------------------------------------------------------------
__global__ void __launch_bounds__(256) prep_kernel(
    const float4* __restrict__ X, u16* __restrict__ xb,
    const float* __restrict__ Wq, const float* __restrict__ Wk,
    const float* __restrict__ Wv,
    u16* __restrict__ Oq, u16* __restrict__ Ok, u16* __restrict__ Ov,
    float* __restrict__ rowsum) {
    __shared__ float tile[32][33];
    const int bid = blockIdx.x, tid = threadIdx.x;
    if (bid < 8192) {
        int idx = bid * 256 + tid;
        float4 v = X[idx];
        ushort4 o;
        o.x = f2bf(v.x); o.y = f2bf(v.y); o.z = f2bf(v.z); o.w = f2bf(v.w);
        *(ushort4*)(xb + (size_t)idx * 4) = o;
    } else if (bid < 11264) {
        int id = bid - 8192;
        int zz = id >> 10;
        const float* W = (zz == 0) ? Wq : (zz == 1) ? Wk : Wv;
        u16* O = (zz == 0) ? Oq : (zz == 1) ? Ok : Ov;
        int n0 = (id & 31) * 32, k0 = ((id >> 5) & 31) * 32;
        int tx = tid & 31, ty = tid >> 5;
        #pragma unroll
        for (int j = 0; j < 32; j += 8)
            tile[ty + j][tx] = W[(size_t)(k0 + ty + j) * 1024 + n0 + tx];
        __syncthreads();
        #pragma unroll
        for (int j = 0; j < 32; j += 8)
            O[(size_t)(n0 + ty + j) * 1024 + k0 + tx] = f2bf(tile[tx][ty + j]);
    } else {
        rowsum[(bid - 11264) * 256 + tid] = 0.f;
    }
}

// ---------------------------------------------------------------
// combine: out[z][1024+r][:] = (out + P1) * inv(rowsum) for the
// split-K rows (1024..2047 per batch). 4096 blocks x 256 threads,
// one float4 per lane: 16 Mi floats.
// ---------------------------------------------------------------
__global__ void __launch_bounds__(256) combine_kernel(
    const float4* __restrict__ P1, const float* __restrict__ rowsum,
    float4* __restrict__ out) {
    int b = blockIdx.x;                        // 0..4095
    int z = b >> 10;
    int i = (b & 1023) * 256 + threadIdx.x;    // 0..262143 float4 within z
    int r = i >> 8;                            // 256 float4 per row
    float inv = 1.0f / rowsum[z * 2048 + 1024 + r];
    size_t oi = (size_t)z * (2048 * 1024 / 4) + (1024 * 1024 / 4) + i;
    float4 a = out[oi];
    float4 p = P1[(size_t)z * (1024 * 1024 / 4) + i];
    a.x = (a.x + p.x) * inv;
    a.y = (a.y + p.y) * inv;
    a.z = (a.z + p.z) * inv;
    a.w = (a.w + p.w) * inv;
    out[oi] = a;
}

// ---------------------------------------------------------------
// NT bf16 GEMM, 128x128 tile, 512 threads = 8 waves in a 2x4 grid,
// each wave computes 64x32 (acc = 8 f32x4). BK=64 single-buffer LDS,
// stage-all -> barrier -> 32 MFMAs -> barrier. XOR-swizzled chunks:
// conflict-free. XCD-clustered decodes. Per-mode LDS pad fingerprints
// the modes in rocprof (32768 / 33280 / 33792 B).
//
// MODE 0: QKV projections (1536 blocks; z=0/1 -> Q/K, z=2 -> Vt[b][d][s]).
// MODE 1: P~ = exp(QK^T/32 - 12) into S, live causal tiles, rowsum
//         via shfl + one fp32 atomic per 16 lanes (768 blocks).
// MODE 2: O~ = P~ V; split-K (NO atomics) for mtile>=8: kh=0 half ->
//         raw partial into P1 (dead xb region), kh=1 half -> raw into
//         out; full tiles (mtile<8) -> normalized out. LPT dispatch
//         order via cls_m/cls_h; Vt XCD-local (768 blocks). A later
//         combine_kernel merges+normalizes rows 1024..2047.
// ---------------------------------------------------------------
template <int MODE>
__global__ void __launch_bounds__(512) gemm_nt(
    const u16* __restrict__ xb, const u16* __restrict__ WqT,
    const u16* __restrict__ WkT, const u16* __restrict__ WvT,
    u16* __restrict__ Q, u16* __restrict__ Kb,
    u16* __restrict__ Vt, u16* __restrict__ S,
    float* __restrict__ rowsum, float* __restrict__ out,
    float* __restrict__ P1) {

    int mtile, ntile, z, kbeg = 0, kiters, kh = 2;
    const u16 *A, *B;

    if (MODE == 0) {
        int L = blockIdx.x;                       // 1536 blocks
        int c = L & 7, t = (L >> 3) & 7, hi = L >> 6;
        int p = hi * 8 + c;                       // 0..191; mtile&7 == c
        z = p >> 6; mtile = p & 63; ntile = t;
        A = xb;
        B = (z == 0) ? WqT : (z == 1) ? WkT : WvT;
        kiters = 16;
    } else if (MODE == 1) {
        int id2 = blockIdx.x;                     // 768 blocks, 544 live
        z = id2 / 192;
        int r = id2 - z * 192;
        int c = r & 7, g = r >> 3;
        if (g <= c)            { mtile = c;     ntile = g; }
        else if (g < 2*c + 10) { mtile = c + 8; ntile = g - (c + 1); }
        else return;
        A = Q  + (size_t)z * (2048 * 1024);
        B = Kb + (size_t)z * (2048 * 1024);
        kiters = 16;
    } else {
        int L = blockIdx.x;                       // 768 blocks
        ntile = L & 7;                            // Vt XCD-local
        int j = L >> 3;
        z = j & 3;
        int ci = j >> 2;                          // 0..23, LPT class order
        mtile = cls_m[ci];
        kh = cls_h[ci];
        kbeg = (kh != 2) ? kh * (mtile + 1) : 0;  // BK64 units
        kiters = (kh != 2) ? (mtile + 1) : (mtile + 1) * 2;
        A = S  + (size_t)z * (2048 * 2048);
        B = Vt + (size_t)z * (1024 * 2048);
    }

    const int LDA = (MODE == 2) ? 2048 : 1024;

    __shared__ __align__(16) u16 As[128 * 64];   // two 32-K halves
    __shared__ __align__(16) u16 Bs[128 * 64 + MODE * 256];  // +fingerprint pad

    const int tid = threadIdx.x;
    const int lane = tid & 63;
    const int wave = tid >> 6;                   // 0..7
    const int wr = wave >> 2, wc = wave & 3;     // 2 x 4 wave grid

    // staging: 512 lanes cover 128 rows x 4 chunks of 16B per half
    const int r0 = tid >> 2;                     // 0..127
    const int kb = (((tid & 3) ^ ((r0 >> 1) & 3))) * 16;   // swizzled chunk

    const char* gA = (const char*)(A + (size_t)(mtile * 128 + r0) * LDA) + kb + kbeg * 128;
    const char* gB = (const char*)(B + (size_t)(ntile * 128 + r0) * LDA) + kb + kbeg * 128;

    char* lA = (char*)As + tid * 16;             // half 1 at +8192 B
    char* lB = (char*)Bs + tid * 16;

    f32x4 acc[4][2] = {};

    const int quad = lane >> 4;
    const int l16 = lane & 15;
    const int ch = quad ^ ((l16 >> 1) & 3);      // de-swizzle on read
    const int aoff = (wr * 64 + l16) * 32 + ch * 8;
    const int boff = (wc * 32 + l16) * 32 + ch * 8;

    for (int kt = 0; kt < kiters; ++kt) {
        load_lds16(gA,      lA);
        load_lds16(gA + 64, lA + 8192);
        load_lds16(gB,      lB);
        load_lds16(gB + 64, lB + 8192);
        gA += 128; gB += 128;
        __syncthreads();

        #pragma unroll
        for (int h = 0; h < 2; ++h) {
            const u16* ap = As + h * 4096 + aoff;
            const u16* bp = Bs + h * 4096 + boff;
            bf16x8 af[4], bfv[2];
            #pragma unroll
            for (int r = 0; r < 4; ++r) af[r] = *(const bf16x8*)(ap + r * 512);
            #pragma unroll
            for (int c = 0; c < 2; ++c) bfv[c] = *(const bf16x8*)(bp + c * 512);
            #pragma unroll
            for (int r = 0; r < 4; ++r)
                #pragma unroll
                for (int c = 0; c < 2; ++c)
                    acc[r][c] = __builtin_amdgcn_mfma_f32_16x16x32_bf16(
                        af[r], bfv[c], acc[r][c], 0, 0, 0);
        }
        __syncthreads();
    }

    // epilogue — C/D layout: col = lane&15, row = (lane>>4)*4 + reg
    const int grow0 = mtile * 128 + wr * 64 + quad * 4;
    const int gcol0 = ntile * 128 + wc * 32 + l16;

    if (MODE == 0) {
        if (z < 2) {
            u16* C = z ? Kb : Q;
            #pragma unroll
            for (int r = 0; r < 4; ++r)
                #pragma unroll
                for (int c = 0; c < 2; ++c)
                    #pragma unroll
                    for (int i = 0; i < 4; ++i)
                        C[(size_t)(grow0 + r * 16 + i) * 1024 + gcol0 + c * 16] =
                            f2bf(acc[r][c][i]);
        } else {
            // Vt[b][d][s]: m -> (b,s), n -> d; 4 consecutive i -> consecutive s
            #pragma unroll
            for (int r = 0; r < 4; ++r) {
                int m0 = grow0 + r * 16;
                int b = m0 >> 11, s0 = m0 & 2047;
                #pragma unroll
                for (int c = 0; c < 2; ++c) {
                    int d = gcol0 + c * 16;
                    ushort4 o;
                    o.x = f2bf(acc[r][c][0]); o.y = f2bf(acc[r][c][1]);
                    o.z = f2bf(acc[r][c][2]); o.w = f2bf(acc[r][c][3]);
                    *(ushort4*)(Vt + (size_t)b * (1024 * 2048) + (size_t)d * 2048 + s0) = o;
                }
            }
        }
    } else if (MODE == 1) {
        u16* C = S + (size_t)z * (2048 * 2048);
        float* rs = rowsum + z * 2048;
        const bool diag = (ntile == mtile);
        float rsum[4][4];
        #pragma unroll
        for (int r = 0; r < 4; ++r)
            #pragma unroll
            for (int i = 0; i < 4; ++i) rsum[r][i] = 0.f;
        #pragma unroll
        for (int r = 0; r < 4; ++r)
            #pragma unroll
            for (int c = 0; c < 2; ++c)
                #pragma unroll
                for (int i = 0; i < 4; ++i) {
                    int grow = grow0 + r * 16 + i;
                    int gcol = gcol0 + c * 16;
                    float e = 0.f;
                    if (!diag || gcol <= grow)
                        e = __expf(acc[r][c][i] * 0.03125f - 12.0f);
                    C[(size_t)grow * 2048 + gcol] = f2bf(e);
                    rsum[r][i] += e;
                }
        #pragma unroll
        for (int r = 0; r < 4; ++r)
            #pragma unroll
            for (int i = 0; i < 4; ++i) {
                float s = rsum[r][i];
                s += __shfl_xor(s, 1, 64);
                s += __shfl_xor(s, 2, 64);
                s += __shfl_xor(s, 4, 64);
                s += __shfl_xor(s, 8, 64);
                if (l16 == 0)
                    unsafeAtomicAdd(&rs[grow0 + r * 16 + i], s);
            }
    } else {  // MODE 2
        if (kh == 2) {
            // full tile: normalize and store
            const float* rs = rowsum + z * 2048;
            float* C = out + (size_t)z * (2048 * 1024);
            #pragma unroll
            for (int r = 0; r < 4; ++r)
                #pragma unroll
                for (int i = 0; i < 4; ++i) {
                    int grow = grow0 + r * 16 + i;
                    float inv = 1.0f / rs[grow];
                    #pragma unroll
                    for (int c = 0; c < 2; ++c)
                        C[(size_t)grow * 1024 + gcol0 + c * 16] = acc[r][c][i] * inv;
                }
        } else if (kh == 1) {
            // raw partial straight into out (combined+normalized later)
            float* C = out + (size_t)z * (2048 * 1024);
            #pragma unroll
            for (int r = 0; r < 4; ++r)
                #pragma unroll
                for (int i = 0; i < 4; ++i) {
                    int grow = grow0 + r * 16 + i;
                    #pragma unroll
                    for (int c = 0; c < 2; ++c)
                        C[(size_t)grow * 1024 + gcol0 + c * 16] = acc[r][c][i];
                }
        } else {
            // raw partial into P1 (rows 1024..2047 -> 0..1023)
            float* Pp = P1 + (size_t)z * (1024 * 1024);
            #pragma unroll
            for (int r = 0; r < 4; ++r)
                #pragma unroll
                for (int i = 0; i < 4; ++i) {
                    int prow = grow0 + r * 16 + i - 1024;
                    #pragma unroll
                    for (int c = 0; c < 2; ++c)
                        Pp[(size_t)prow * 1024 + gcol0 + c * 16] = acc[r][c][i];
                }
        }
    }
}

// ---------------------------------------------------------------
// launch
// ---------------------------------------------------------------
extern "C" void kernel_launch(void* const* d_in, const int* in_sizes, int n_in,
                              void* d_out, int out_size, void* d_ws, size_t ws_size,
                              hipStream_t stream) {
    const float* x  = (const float*)d_in[0];
    const float* Wq = (const float*)d_in[1];
    const float* Wk = (const float*)d_in[2];
    const float* Wv = (const float*)d_in[3];
    float* out = (float*)d_out;
    char* ws = (char*)d_ws;
    const size_t Mi = 1u << 20;

    u16* xb  = (u16*)(ws);               // [8192][1024] bf16  16 MiB
    u16* WqT = (u16*)(ws + 16 * Mi);     // [1024][1024] bf16   2 MiB
    u16* WkT = (u16*)(ws + 18 * Mi);
    u16* WvT = (u16*)(ws + 20 * Mi);
    u16* Q   = (u16*)(ws + 22 * Mi);     // [8192][1024] bf16  16 MiB
    u16* Kb  = (u16*)(ws + 38 * Mi);
    u16* Vt  = (u16*)(ws + 54 * Mi);     // [4][1024][2048] bf16 16 MiB
    u16* S   = (u16*)(ws + 70 * Mi);     // [4][2048][2048] bf16 32 MiB (P~)
    float* rowsum = (float*)(ws + 102 * Mi);  // [4][2048] fp32
    float* P1 = (float*)xb;              // split-K partials reuse dead xb (16 MiB)

    // prep: cast x + transpose W + zero rowsum
    prep_kernel<<<11296, 256, 0, stream>>>(
        (const float4*)x, xb, Wq, Wk, Wv, WqT, WkT, WvT, rowsum);

    // QKV projections (z: 0=Q, 1=K, 2=Vt)
    gemm_nt<0><<<1536, 512, 0, stream>>>(xb, WqT, WkT, WvT, Q, Kb, Vt, S, rowsum, out, P1);

    // P~ = exp(QK^T/32 - 12) + rowsum, live causal tiles
    gemm_nt<1><<<768, 512, 0, stream>>>(xb, WqT, WkT, WvT, Q, Kb, Vt, S, rowsum, out, P1);

    // O~ = P~ V, split-K heavy tiles (no atomics), LPT order
    gemm_nt<2><<<768, 512, 0, stream>>>(xb, WqT, WkT, WvT, Q, Kb, Vt, S, rowsum, out, P1);

    // merge + normalize split-K rows
    combine_kernel<<<4096, 256, 0, stream>>>(
        (const float4*)P1, rowsum, (float4*)out);
}